// Round 1
// baseline (450.429 us; speedup 1.0000x reference)
//
#include <hip/hip_runtime.h>
#include <hip/hip_bf16.h>

// EncoderLayer on MI355X (gfx950).
// B=2, S=2048, D=1024, H=16, DK=64. M = B*S = 4096.
// Pipeline: LN1 -> fused QKV GEMM -> flash attention -> O GEMM (+X residual, f32)
//           -> LN2 -> FF1 (+bias, exact GELU) -> FF2 (+bias, +residual) -> d_out (f32)
// All matmuls in bf16 MFMA (16x16x32), f32 accumulate. Weights transposed to
// (N x K) bf16 in workspace so GEMM B-operand fragments are contiguous-K.

using bf16 = __hip_bfloat16;
typedef __attribute__((ext_vector_type(4))) float f32x4;
typedef __attribute__((ext_vector_type(8))) short bf16x8;

#define DEVI static __device__ __forceinline__

DEVI void async_copy16(const void* g, void* l) {
  __builtin_amdgcn_global_load_lds(
      (const __attribute__((address_space(1))) void*)g,
      (__attribute__((address_space(3))) void*)l, 16, 0, 0);
}

DEVI ushort f2bf_bits(float v) {
  __hip_bfloat16 h = __float2bfloat16(v);
  return *reinterpret_cast<ushort*>(&h);
}

// ---------------- LayerNorm: f32 in (rows x 1024) -> bf16 out ----------------
__global__ __launch_bounds__(256) void ln_kernel(
    const float* __restrict__ in, const float* __restrict__ gamma,
    const float* __restrict__ beta, bf16* __restrict__ out) {
  const long row = blockIdx.x;
  const int t = threadIdx.x;
  float4 x = ((const float4*)(in + row * 1024))[t];
  float s = x.x + x.y + x.z + x.w;
  float s2 = x.x * x.x + x.y * x.y + x.z * x.z + x.w * x.w;
#pragma unroll
  for (int m = 1; m < 64; m <<= 1) {
    s += __shfl_xor(s, m);
    s2 += __shfl_xor(s2, m);
  }
  __shared__ float red[8];
  const int w = t >> 6, l = t & 63;
  if (l == 0) { red[w] = s; red[4 + w] = s2; }
  __syncthreads();
  s = red[0] + red[1] + red[2] + red[3];
  s2 = red[4] + red[5] + red[6] + red[7];
  const float mean = s * (1.0f / 1024.0f);
  const float var = s2 * (1.0f / 1024.0f) - mean * mean;
  const float rstd = rsqrtf(var + 1e-6f);
  float4 g4 = ((const float4*)gamma)[t];
  float4 b4 = ((const float4*)beta)[t];
  union { ushort h[4]; uint2 u; } o;
  o.h[0] = f2bf_bits(g4.x * (x.x - mean) * rstd + b4.x);
  o.h[1] = f2bf_bits(g4.y * (x.y - mean) * rstd + b4.y);
  o.h[2] = f2bf_bits(g4.z * (x.z - mean) * rstd + b4.z);
  o.h[3] = f2bf_bits(g4.w * (x.w - mean) * rstd + b4.w);
  ((uint2*)(out + row * 1024))[t] = o.u;
}

// ------------- transpose f32 (K x N) -> bf16 (N x K), 32x32 tiles -------------
__global__ __launch_bounds__(256) void transpose_to_bf16(
    const float* __restrict__ W, bf16* __restrict__ Wt, const int K, const int N) {
  __shared__ float tile[32][33];
  const int tx = threadIdx.x & 31, ty = threadIdx.x >> 5;  // 32 x 8
  const int n0 = blockIdx.x << 5, k0 = blockIdx.y << 5;
#pragma unroll
  for (int i = 0; i < 32; i += 8)
    tile[ty + i][tx] = W[(long)(k0 + ty + i) * N + n0 + tx];
  __syncthreads();
#pragma unroll
  for (int i = 0; i < 32; i += 8)
    Wt[(long)(n0 + ty + i) * K + k0 + tx] = __float2bfloat16(tile[tx][ty + i]);
}

// ---------------- GEMM: C(MxN) = A(MxK,bf16) * Bt(NxK,bf16)^T ----------------
// 128x128 tile, BK=32, 4 waves (each 64x64), global_load_lds staging (m97 structure).
// EPI: 0 = store bf16; 1 = +res(f32) store f32; 2 = +bias, exact GELU, store bf16;
//      3 = +bias +res(f32) store f32.
template <int EPI>
__global__ __launch_bounds__(256) void gemm_bt(
    const bf16* __restrict__ A, const bf16* __restrict__ Bt,
    const int M, const int N, const int K,
    const float* __restrict__ bias, const float* __restrict__ res,
    void* __restrict__ Cout) {
  __shared__ bf16 As[128 * 32];
  __shared__ bf16 Bs[128 * 32];
  const int t = threadIdx.x;
  const int w = t >> 6, l = t & 63;
  const int nb = N >> 7;
  const int bm = blockIdx.x / nb, bn = blockIdx.x % nb;
  const long row0 = (long)bm << 7, col0 = (long)bn << 7;
  const int wr = (w >> 1) << 6, wc = (w & 1) << 6;
  const int lr = l & 15, lk = (l >> 4) << 3;  // frag row-in-16, k elem offset in 32

  f32x4 acc[4][4];
#pragma unroll
  for (int m = 0; m < 4; ++m)
#pragma unroll
    for (int n = 0; n < 4; ++n) acc[m][n] = (f32x4){0.f, 0.f, 0.f, 0.f};

  const bf16* gA = A + (row0 + (t >> 2)) * K + ((t & 3) << 3);
  const bf16* gB = Bt + (col0 + (t >> 2)) * K + ((t & 3) << 3);
  char* lA = (char*)As + (w << 10);
  char* lB = (char*)Bs + (w << 10);
  const long k64 = (long)64 * K;

  for (int k0 = 0; k0 < K; k0 += 32) {
    __syncthreads();
    async_copy16(gA + k0, lA);
    async_copy16(gA + k64 + k0, lA + 4096);
    async_copy16(gB + k0, lB);
    async_copy16(gB + k64 + k0, lB + 4096);
    __syncthreads();
    bf16x8 af[4], bfr[4];
#pragma unroll
    for (int m = 0; m < 4; ++m)
      af[m] = *(const bf16x8*)&As[(wr + m * 16 + lr) * 32 + lk];
#pragma unroll
    for (int n = 0; n < 4; ++n)
      bfr[n] = *(const bf16x8*)&Bs[(wc + n * 16 + lr) * 32 + lk];
#pragma unroll
    for (int m = 0; m < 4; ++m)
#pragma unroll
      for (int n = 0; n < 4; ++n)
        acc[m][n] = __builtin_amdgcn_mfma_f32_16x16x32_bf16(af[m], bfr[n], acc[m][n], 0, 0, 0);
  }

  bf16* Cb = (bf16*)Cout;
  float* Cf = (float*)Cout;
#pragma unroll
  for (int m = 0; m < 4; ++m) {
#pragma unroll
    for (int r = 0; r < 4; ++r) {
      const long crow = row0 + wr + m * 16 + ((l >> 4) << 2) + r;
      const long rbase = crow * N;
#pragma unroll
      for (int n = 0; n < 4; ++n) {
        const long ccol = col0 + wc + n * 16 + lr;
        float v = acc[m][n][r];
        if (EPI == 2) {
          v += bias[ccol];
          v = 0.5f * v * (1.0f + erff(v * 0.70710678118654752f));
        }
        if (EPI == 3) v += bias[ccol] + res[rbase + ccol];
        if (EPI == 1) v += res[rbase + ccol];
        if (EPI == 0 || EPI == 2)
          Cb[rbase + ccol] = __float2bfloat16(v);
        else
          Cf[rbase + ccol] = v;
      }
    }
  }
}

// ---------------- flash attention ----------------
// Grid: x = S/64 q-tiles, y = B*H. Block 256 = 4 waves; wave w owns q rows w*16..w*16+15.
// QKV: (4096 x 3072) bf16, Q|K|V each 1024-wide, head h at col h*64.
// LDS tiles [64][64] bf16 (128B rows) with XOR swizzle byte ^= (row&7)<<4 (G4).
__global__ __launch_bounds__(256) void attn_kernel(
    const bf16* __restrict__ QKV, const int* __restrict__ pmask,
    bf16* __restrict__ Oout) {
  const int bh = blockIdx.y;
  const int b = bh >> 4, h = bh & 15;
  const int q0 = blockIdx.x << 6;
  const int t = threadIdx.x;
  const int w = t >> 6, l = t & 63;
  const int lr = l & 15;
  const int lkb = (l >> 4) << 4;  // byte offset of lane's 8-elem k group

  __shared__ bf16 Qs[64 * 64], Ks[64 * 64], Vt[64 * 64], Ps[64 * 64];

  const long base = (long)b * 2048 * 3072;
  const bf16* Qg = QKV + base + h * 64;
  const bf16* Kg = QKV + base + 1024 + h * 64;
  const bf16* Vg = QKV + base + 2048 + h * 64;

#pragma unroll
  for (int p = 0; p < 2; ++p) {
    const int c = p * 256 + t, r = c >> 3, sg = c & 7;
    uint4 qv = *(const uint4*)(Qg + (long)(q0 + r) * 3072 + sg * 8);
    const int addr = (r * 128 + sg * 16) ^ ((r & 7) << 4);
    *(uint4*)((char*)Qs + addr) = qv;
  }
  __syncthreads();

  float mrun[4] = {-3.0e38f, -3.0e38f, -3.0e38f, -3.0e38f};
  float lrun[4] = {0.f, 0.f, 0.f, 0.f};
  f32x4 oacc[4];
#pragma unroll
  for (int dt = 0; dt < 4; ++dt) oacc[dt] = (f32x4){0.f, 0.f, 0.f, 0.f};

  for (int kt = 0; kt < 32; ++kt) {
    const int k0 = kt << 6;
    __syncthreads();  // previous iteration's PV reads done before overwrite
#pragma unroll
    for (int p = 0; p < 2; ++p) {
      const int c = p * 256 + t, r = c >> 3, sg = c & 7;
      uint4 kv = *(const uint4*)(Kg + (long)(k0 + r) * 3072 + sg * 8);
      const int addr = (r * 128 + sg * 16) ^ ((r & 7) << 4);
      *(uint4*)((char*)Ks + addr) = kv;
      uint4 vv = *(const uint4*)(Vg + (long)(k0 + r) * 3072 + sg * 8);
      const ushort* vs = (const ushort*)&vv;
#pragma unroll
      for (int e = 0; e < 8; ++e) {
        const int d = sg * 8 + e;
        const int vaddr = (d * 128 + r * 2) ^ ((d & 7) << 4);
        *(ushort*)((char*)Vt + vaddr) = vs[e];
      }
    }
    __syncthreads();

    // S = Q K^T (16 q-rows x 64 kv per wave)
    f32x4 sacc[4];
#pragma unroll
    for (int nt = 0; nt < 4; ++nt) sacc[nt] = (f32x4){0.f, 0.f, 0.f, 0.f};
#pragma unroll
    for (int ks = 0; ks < 2; ++ks) {
      const int qrow = w * 16 + lr;
      const int cb = ks * 64 + lkb;
      bf16x8 aq = *(const bf16x8*)((const char*)Qs + ((qrow * 128 + cb) ^ ((qrow & 7) << 4)));
#pragma unroll
      for (int nt = 0; nt < 4; ++nt) {
        const int krow = nt * 16 + lr;
        bf16x8 bk = *(const bf16x8*)((const char*)Ks + ((krow * 128 + cb) ^ ((krow & 7) << 4)));
        sacc[nt] = __builtin_amdgcn_mfma_f32_16x16x32_bf16(aq, bk, sacc[nt], 0, 0, 0);
      }
    }

    int mv[4];
#pragma unroll
    for (int nt = 0; nt < 4; ++nt) mv[nt] = pmask[b * 2048 + k0 + nt * 16 + lr];

    // online softmax; lane holds cols (nt*16+lr) for rows (l>>4)*4+r
#pragma unroll
    for (int r = 0; r < 4; ++r) {
      float sv[4], smax = -3.0e38f;
#pragma unroll
      for (int nt = 0; nt < 4; ++nt) {
        float sc = sacc[nt][r] * 0.125f;
        if (mv[nt] == 0) sc = -1.0e9f;
        sv[nt] = sc;
        smax = fmaxf(smax, sc);
      }
#pragma unroll
      for (int mm = 1; mm < 16; mm <<= 1) smax = fmaxf(smax, __shfl_xor(smax, mm));
      const float Mn = fmaxf(mrun[r], smax);
      const float alpha = __expf(mrun[r] - Mn);
      mrun[r] = Mn;
      float psum = 0.f;
      ushort pb[4];
#pragma unroll
      for (int nt = 0; nt < 4; ++nt) {
        const float p = __expf(sv[nt] - Mn);
        psum += p;
        pb[nt] = f2bf_bits(p);
      }
#pragma unroll
      for (int mm = 1; mm < 16; mm <<= 1) psum += __shfl_xor(psum, mm);
      lrun[r] = lrun[r] * alpha + psum;
#pragma unroll
      for (int dt = 0; dt < 4; ++dt) oacc[dt][r] *= alpha;
      const int prow = w * 16 + ((l >> 4) << 2) + r;
#pragma unroll
      for (int nt = 0; nt < 4; ++nt) {
        const int paddr = (prow * 128 + (nt * 16 + lr) * 2) ^ ((prow & 7) << 4);
        *(ushort*)((char*)Ps + paddr) = pb[nt];
      }
    }
    __syncthreads();  // Ps visible (and wave-local write->read ordering)

    // O += P V
#pragma unroll
    for (int ks = 0; ks < 2; ++ks) {
      const int prow = w * 16 + lr;
      const int cb = ks * 64 + lkb;
      bf16x8 ap = *(const bf16x8*)((const char*)Ps + ((prow * 128 + cb) ^ ((prow & 7) << 4)));
#pragma unroll
      for (int dt = 0; dt < 4; ++dt) {
        const int vrow = dt * 16 + lr;
        bf16x8 bv = *(const bf16x8*)((const char*)Vt + ((vrow * 128 + cb) ^ ((vrow & 7) << 4)));
        oacc[dt] = __builtin_amdgcn_mfma_f32_16x16x32_bf16(ap, bv, oacc[dt], 0, 0, 0);
      }
    }
  }

#pragma unroll
  for (int r = 0; r < 4; ++r) {
    const float inv = 1.0f / lrun[r];
    const long orow = (long)b * 2048 + q0 + w * 16 + ((l >> 4) << 2) + r;
    const long ob = orow * 1024 + h * 64;
#pragma unroll
    for (int dt = 0; dt < 4; ++dt)
      Oout[ob + dt * 16 + lr] = __float2bfloat16(oacc[dt][r] * inv);
  }
}

extern "C" void kernel_launch(void* const* d_in, const int* in_sizes, int n_in,
                              void* d_out, int out_size, void* d_ws, size_t ws_size,
                              hipStream_t stream) {
  const float* X = (const float*)d_in[0];
  const int* pmask = (const int*)d_in[1];
  const float* W_Q = (const float*)d_in[2];
  const float* W_K = (const float*)d_in[3];
  const float* W_V = (const float*)d_in[4];
  const float* W_O = (const float*)d_in[5];
  const float* g1 = (const float*)d_in[6];
  const float* b1 = (const float*)d_in[7];
  const float* W1 = (const float*)d_in[8];
  const float* bias1 = (const float*)d_in[9];
  const float* W2 = (const float*)d_in[10];
  const float* bias2 = (const float*)d_in[11];
  const float* g2 = (const float*)d_in[12];
  const float* b2 = (const float*)d_in[13];
  (void)in_sizes; (void)n_in; (void)out_size; (void)ws_size;

  char* ws = (char*)d_ws;
  const size_t MB = 1ull << 20;
  // workspace layout (80 MB total), ff1 overlaps dead QKV+attn:
  bf16* Wqkv_t = (bf16*)(ws + 0);         // 3072 x 1024   (6 MB)
  bf16* Wo_t   = (bf16*)(ws + 6 * MB);    // 1024 x 1024   (2 MB)
  bf16* W1_t   = (bf16*)(ws + 8 * MB);    // 4096 x 1024   (8 MB)
  bf16* W2_t   = (bf16*)(ws + 16 * MB);   // 1024 x 4096   (8 MB)
  bf16* xn     = (bf16*)(ws + 24 * MB);   // 4096 x 1024   (8 MB, reused as nn2)
  bf16* QKV    = (bf16*)(ws + 32 * MB);   // 4096 x 3072   (24 MB)
  bf16* attnb  = (bf16*)(ws + 56 * MB);   // 4096 x 1024   (8 MB)
  float* res1  = (float*)(ws + 64 * MB);  // 4096 x 1024 f32 (16 MB)
  bf16* ff1    = (bf16*)(ws + 32 * MB);   // 4096 x 4096   (32 MB) over QKV+attnb

  // weight convert + transpose (f32 KxN -> bf16 NxK)
  transpose_to_bf16<<<dim3(32, 32), 256, 0, stream>>>(W_Q, Wqkv_t, 1024, 1024);
  transpose_to_bf16<<<dim3(32, 32), 256, 0, stream>>>(W_K, Wqkv_t + (size_t)1024 * 1024, 1024, 1024);
  transpose_to_bf16<<<dim3(32, 32), 256, 0, stream>>>(W_V, Wqkv_t + (size_t)2048 * 1024, 1024, 1024);
  transpose_to_bf16<<<dim3(32, 32), 256, 0, stream>>>(W_O, Wo_t, 1024, 1024);
  transpose_to_bf16<<<dim3(128, 32), 256, 0, stream>>>(W1, W1_t, 1024, 4096);
  transpose_to_bf16<<<dim3(32, 128), 256, 0, stream>>>(W2, W2_t, 4096, 1024);

  // LN1
  ln_kernel<<<4096, 256, 0, stream>>>(X, g1, b1, xn);
  // fused QKV projection
  gemm_bt<0><<<32 * 24, 256, 0, stream>>>(xn, Wqkv_t, 4096, 3072, 1024, nullptr, nullptr, QKV);
  // attention
  attn_kernel<<<dim3(32, 32), 256, 0, stream>>>(QKV, pmask, attnb);
  // O projection + residual (f32)
  gemm_bt<1><<<32 * 8, 256, 0, stream>>>(attnb, Wo_t, 4096, 1024, 1024, nullptr, X, res1);
  // LN2
  ln_kernel<<<4096, 256, 0, stream>>>(res1, g2, b2, xn);
  // FF1 + bias + exact GELU
  gemm_bt<2><<<32 * 32, 256, 0, stream>>>(xn, W1_t, 4096, 4096, 1024, bias1, nullptr, ff1);
  // FF2 + bias + residual -> final f32 output
  gemm_bt<3><<<32 * 8, 256, 0, stream>>>(ff1, W2_t, 4096, 1024, 4096, bias2, res1, (float*)d_out);
}

// Round 2
// 374.691 us; speedup vs baseline: 1.2021x; 1.2021x over previous
//
#include <hip/hip_runtime.h>
#include <hip/hip_bf16.h>

// EncoderLayer on MI355X (gfx950).
// B=2, S=2048, D=1024, H=16, DK=64. M = B*S = 4096.
// Pipeline: LN1 -> fused QKV GEMM -> flash attention -> O GEMM (+X residual, f32)
//           -> LN2 -> FF1 (+bias, exact GELU) -> FF2 (+bias, +residual) -> d_out (f32)
// R2: attention rewritten to swapped-QK^T 32x32 MFMA structure (m214 ladder):
//   - S^T = mfma(K, Q^T): lane owns one q column -> in-lane softmax + 1 shfl_xor(32)
//   - P stays in registers; A-fragments built via bf16 pack + lane^32 exchange (T12)
//   - V^T scatter-store with (k*2)^(((d&7)^((d>>3)&7))<<4) swizzle (conflict-free writes)
//   - mask folded in via one rank-1 MFMA per 32-k tile
//   - defer-rescale: skip O-rescale when __any(tmax > m) is false

using bf16 = __hip_bfloat16;
typedef __attribute__((ext_vector_type(4))) float f32x4;
typedef __attribute__((ext_vector_type(16))) float f32x16;
typedef __attribute__((ext_vector_type(8))) short bf16x8;

#define DEVI static __device__ __forceinline__

DEVI void async_copy16(const void* g, void* l) {
  __builtin_amdgcn_global_load_lds(
      (const __attribute__((address_space(1))) void*)g,
      (__attribute__((address_space(3))) void*)l, 16, 0, 0);
}

DEVI ushort f2bf_bits(float v) {
  __hip_bfloat16 h = __float2bfloat16(v);
  return *reinterpret_cast<ushort*>(&h);
}

DEVI float bfbits2f(ushort u) {
  union { float f; unsigned int i; } x;
  x.i = ((unsigned int)u) << 16;
  return x.f;
}

DEVI unsigned int pk2(float lo, float hi) {
  return (unsigned int)f2bf_bits(lo) | ((unsigned int)f2bf_bits(hi) << 16);
}

// ---------------- LayerNorm: f32 in (rows x 1024) -> bf16 out ----------------
__global__ __launch_bounds__(256) void ln_kernel(
    const float* __restrict__ in, const float* __restrict__ gamma,
    const float* __restrict__ beta, bf16* __restrict__ out) {
  const long row = blockIdx.x;
  const int t = threadIdx.x;
  float4 x = ((const float4*)(in + row * 1024))[t];
  float s = x.x + x.y + x.z + x.w;
  float s2 = x.x * x.x + x.y * x.y + x.z * x.z + x.w * x.w;
#pragma unroll
  for (int m = 1; m < 64; m <<= 1) {
    s += __shfl_xor(s, m);
    s2 += __shfl_xor(s2, m);
  }
  __shared__ float red[8];
  const int w = t >> 6, l = t & 63;
  if (l == 0) { red[w] = s; red[4 + w] = s2; }
  __syncthreads();
  s = red[0] + red[1] + red[2] + red[3];
  s2 = red[4] + red[5] + red[6] + red[7];
  const float mean = s * (1.0f / 1024.0f);
  const float var = s2 * (1.0f / 1024.0f) - mean * mean;
  const float rstd = rsqrtf(var + 1e-6f);
  float4 g4 = ((const float4*)gamma)[t];
  float4 b4 = ((const float4*)beta)[t];
  union { ushort h[4]; uint2 u; } o;
  o.h[0] = f2bf_bits(g4.x * (x.x - mean) * rstd + b4.x);
  o.h[1] = f2bf_bits(g4.y * (x.y - mean) * rstd + b4.y);
  o.h[2] = f2bf_bits(g4.z * (x.z - mean) * rstd + b4.z);
  o.h[3] = f2bf_bits(g4.w * (x.w - mean) * rstd + b4.w);
  ((uint2*)(out + row * 1024))[t] = o.u;
}

// ------------- transpose f32 (K x N) -> bf16 (N x K), 32x32 tiles -------------
__global__ __launch_bounds__(256) void transpose_to_bf16(
    const float* __restrict__ W, bf16* __restrict__ Wt, const int K, const int N) {
  __shared__ float tile[32][33];
  const int tx = threadIdx.x & 31, ty = threadIdx.x >> 5;  // 32 x 8
  const int n0 = blockIdx.x << 5, k0 = blockIdx.y << 5;
#pragma unroll
  for (int i = 0; i < 32; i += 8)
    tile[ty + i][tx] = W[(long)(k0 + ty + i) * N + n0 + tx];
  __syncthreads();
#pragma unroll
  for (int i = 0; i < 32; i += 8)
    Wt[(long)(n0 + ty + i) * K + k0 + tx] = __float2bfloat16(tile[tx][ty + i]);
}

// ---------------- GEMM: C(MxN) = A(MxK,bf16) * Bt(NxK,bf16)^T ----------------
// 128x128 tile, BK=32, 4 waves (each 64x64), global_load_lds staging (m97 structure).
// EPI: 0 = store bf16; 1 = +res(f32) store f32; 2 = +bias, exact GELU, store bf16;
//      3 = +bias +res(f32) store f32.
template <int EPI>
__global__ __launch_bounds__(256) void gemm_bt(
    const bf16* __restrict__ A, const bf16* __restrict__ Bt,
    const int M, const int N, const int K,
    const float* __restrict__ bias, const float* __restrict__ res,
    void* __restrict__ Cout) {
  __shared__ bf16 As[128 * 32];
  __shared__ bf16 Bs[128 * 32];
  const int t = threadIdx.x;
  const int w = t >> 6, l = t & 63;
  const int nb = N >> 7;
  const int bm = blockIdx.x / nb, bn = blockIdx.x % nb;
  const long row0 = (long)bm << 7, col0 = (long)bn << 7;
  const int wr = (w >> 1) << 6, wc = (w & 1) << 6;
  const int lr = l & 15, lk = (l >> 4) << 3;  // frag row-in-16, k elem offset in 32

  f32x4 acc[4][4];
#pragma unroll
  for (int m = 0; m < 4; ++m)
#pragma unroll
    for (int n = 0; n < 4; ++n) acc[m][n] = (f32x4){0.f, 0.f, 0.f, 0.f};

  const bf16* gA = A + (row0 + (t >> 2)) * K + ((t & 3) << 3);
  const bf16* gB = Bt + (col0 + (t >> 2)) * K + ((t & 3) << 3);
  char* lA = (char*)As + (w << 10);
  char* lB = (char*)Bs + (w << 10);
  const long k64 = (long)64 * K;

  for (int k0 = 0; k0 < K; k0 += 32) {
    __syncthreads();
    async_copy16(gA + k0, lA);
    async_copy16(gA + k64 + k0, lA + 4096);
    async_copy16(gB + k0, lB);
    async_copy16(gB + k64 + k0, lB + 4096);
    __syncthreads();
    bf16x8 af[4], bfr[4];
#pragma unroll
    for (int m = 0; m < 4; ++m)
      af[m] = *(const bf16x8*)&As[(wr + m * 16 + lr) * 32 + lk];
#pragma unroll
    for (int n = 0; n < 4; ++n)
      bfr[n] = *(const bf16x8*)&Bs[(wc + n * 16 + lr) * 32 + lk];
#pragma unroll
    for (int m = 0; m < 4; ++m)
#pragma unroll
      for (int n = 0; n < 4; ++n)
        acc[m][n] = __builtin_amdgcn_mfma_f32_16x16x32_bf16(af[m], bfr[n], acc[m][n], 0, 0, 0);
  }

  bf16* Cb = (bf16*)Cout;
  float* Cf = (float*)Cout;
#pragma unroll
  for (int m = 0; m < 4; ++m) {
#pragma unroll
    for (int r = 0; r < 4; ++r) {
      const long crow = row0 + wr + m * 16 + ((l >> 4) << 2) + r;
      const long rbase = crow * N;
#pragma unroll
      for (int n = 0; n < 4; ++n) {
        const long ccol = col0 + wc + n * 16 + lr;
        float v = acc[m][n][r];
        if (EPI == 2) {
          v += bias[ccol];
          v = 0.5f * v * (1.0f + erff(v * 0.70710678118654752f));
        }
        if (EPI == 3) v += bias[ccol] + res[rbase + ccol];
        if (EPI == 1) v += res[rbase + ccol];
        if (EPI == 0 || EPI == 2)
          Cb[rbase + ccol] = __float2bfloat16(v);
        else
          Cf[rbase + ccol] = v;
      }
    }
  }
}

// ---------------- flash attention (swapped QK^T, 32x32 MFMA) ----------------
// Grid: x = S/128 q-tiles, y = B*H. Block 256 = 4 waves; wave w owns q rows
// [w*32, w*32+32). Per kv-tile (64 k): S^T = mfma(K, Q^T) so each lane owns one
// q column; softmax in-lane + shfl_xor(32); P packed to bf16 in registers and
// exchanged lane<->lane^32 to form PV A-fragments; O = mfma(P, V).
__global__ __launch_bounds__(256) void attn_kernel(
    const bf16* __restrict__ QKV, const int* __restrict__ pmask,
    bf16* __restrict__ Oout) {
  const int bh = blockIdx.y;
  const int b = bh >> 4, h = bh & 15;
  const int q0 = blockIdx.x << 7;  // 128 q rows per block
  const int t = threadIdx.x;
  const int w = t >> 6, l = t & 63;
  const int lq = l & 31, hi = l >> 5;

  __shared__ bf16 Ks[64 * 64];  // [k][d] row-major, swizzled byte ^= (k&7)<<4
  __shared__ bf16 Vt[64 * 64];  // [d][k] row-major, swizzled byte ^= ((d&7)^((d>>3)&7))<<4

  const long base = (long)b * 2048 * 3072;
  const bf16* Qg = QKV + base + h * 64;
  const bf16* Kg = QKV + base + 1024 + h * 64;
  const bf16* Vg = QKV + base + 2048 + h * 64;

  // Q fragments in registers, prescaled by 1/8 (exact power of 2).
  // B-operand of 32x32x16: lane holds col q=lq, k(d) = hi*8+e.
  const int qw0 = q0 + w * 32;
  bf16x8 qf[4];
#pragma unroll
  for (int dc = 0; dc < 4; ++dc) {
    uint4 raw = *(const uint4*)(Qg + (long)(qw0 + lq) * 3072 + dc * 16 + hi * 8);
    union { uint4 u4; ushort us[8]; } in; in.u4 = raw;
    union { bf16x8 v; ushort us[8]; } o;
#pragma unroll
    for (int e = 0; e < 8; ++e) o.us[e] = f2bf_bits(0.125f * bfbits2f(in.us[e]));
    qf[dc] = o.v;
  }

  // B-operand of the mask rank-1 MFMA: B[0][q] = 1
  union { unsigned int u[4]; bf16x8 v; } bones;
  bones.u[0] = (hi == 0) ? 0x00003F80u : 0u;  // bf16(1.0) in e=0 slot
  bones.u[1] = bones.u[2] = bones.u[3] = 0u;

  f32x16 oacc[2];
#pragma unroll
  for (int nt = 0; nt < 2; ++nt)
#pragma unroll
    for (int r = 0; r < 16; ++r) oacc[nt][r] = 0.f;
  float mrun = -3.0e38f, lsum = 0.f;

  for (int ktg = 0; ktg < 32; ++ktg) {
    const int k0 = ktg << 6;
    __syncthreads();  // previous iteration's reads complete
    // ---- stage K (row-major) and V^T (scatter) into LDS ----
#pragma unroll
    for (int p = 0; p < 2; ++p) {
      const int c = p * 256 + t, r = c >> 3, sg = c & 7;
      uint4 kv = *(const uint4*)(Kg + (long)(k0 + r) * 3072 + sg * 8);
      *(uint4*)((char*)Ks + ((r * 128 + sg * 16) ^ ((r & 7) << 4))) = kv;
      uint4 vv = *(const uint4*)(Vg + (long)(k0 + r) * 3072 + sg * 8);
      const ushort* vs = (const ushort*)&vv;
#pragma unroll
      for (int e = 0; e < 8; ++e) {
        const int d = sg * 8 + e;
        *(ushort*)((char*)Vt + (d * 128 + ((r * 2) ^ (((e ^ sg) & 7) << 4)))) = vs[e];
      }
    }
    __syncthreads();

    // ---- S^T = K Q^T : sacc[kt] covers k rows [kt*32, kt*32+32), q cols = lq
    // D layout: lane holds S^T[k = kt*32 + crow(r,hi)][q = lq],
    // crow(r,hi) = (r&3) + 8*(r>>2) + 4*hi
    f32x16 sacc[2];
#pragma unroll
    for (int kt = 0; kt < 2; ++kt) {
#pragma unroll
      for (int r = 0; r < 16; ++r) sacc[kt][r] = 0.f;
#pragma unroll
      for (int dc = 0; dc < 4; ++dc) {
        bf16x8 ka = *(const bf16x8*)((const char*)Ks +
            ((kt * 32 + lq) * 128 + ((dc * 32 + hi * 16) ^ ((lq & 7) << 4))));
        sacc[kt] = __builtin_amdgcn_mfma_f32_32x32x16_bf16(ka, qf[dc], sacc[kt], 0, 0, 0);
      }
      // mask addend as rank-1 MFMA: A[k][0] = (mask ? 0 : -1e9)
      const int mv = pmask[b * 2048 + k0 + kt * 32 + lq];
      union { unsigned int u[4]; bf16x8 v; } aadd;
      aadd.u[0] = (hi == 0 && mv == 0) ? (unsigned int)f2bf_bits(-1.0e9f) : 0u;
      aadd.u[1] = aadd.u[2] = aadd.u[3] = 0u;
      sacc[kt] = __builtin_amdgcn_mfma_f32_32x32x16_bf16(aadd.v, bones.v, sacc[kt], 0, 0, 0);
    }

    // ---- online softmax (lane owns q = lq; lane pair l, l^32 share the row) ----
    float tmax = -3.0e38f;
#pragma unroll
    for (int kt = 0; kt < 2; ++kt)
#pragma unroll
      for (int r = 0; r < 16; ++r) tmax = fmaxf(tmax, sacc[kt][r]);
    tmax = fmaxf(tmax, __shfl_xor(tmax, 32));
    const bool need = (bool)__any(tmax > mrun);
    const float mnew = need ? fmaxf(mrun, tmax) : mrun;
    float psum = 0.f;
#pragma unroll
    for (int kt = 0; kt < 2; ++kt)
#pragma unroll
      for (int r = 0; r < 16; ++r) {
        const float p = __expf(sacc[kt][r] - mnew);
        sacc[kt][r] = p;
        psum += p;
      }
    psum += __shfl_xor(psum, 32);
    if (need) {
      const float alpha = __expf(mrun - mnew);
      mrun = mnew;
      lsum = lsum * alpha + psum;
#pragma unroll
      for (int r = 0; r < 16; ++r) {
        const float ar = __shfl(alpha, (r & 3) + 8 * (r >> 2) + 4 * hi);
        oacc[0][r] *= ar;
        oacc[1][r] *= ar;
      }
    } else {
      lsum += psum;
    }

    // ---- P -> bf16 A-fragments via pack + lane^32 exchange; O += P V ----
#pragma unroll
    for (int kt = 0; kt < 2; ++kt) {
      const unsigned int cs0 = pk2(sacc[kt][0], sacc[kt][1]);
      const unsigned int cs1 = pk2(sacc[kt][2], sacc[kt][3]);
      const unsigned int cs2 = pk2(sacc[kt][4], sacc[kt][5]);
      const unsigned int cs3 = pk2(sacc[kt][6], sacc[kt][7]);
      const unsigned int cs4 = pk2(sacc[kt][8], sacc[kt][9]);
      const unsigned int cs5 = pk2(sacc[kt][10], sacc[kt][11]);
      const unsigned int cs6 = pk2(sacc[kt][12], sacc[kt][13]);
      const unsigned int cs7 = pk2(sacc[kt][14], sacc[kt][15]);
      const unsigned int es0 = __shfl_xor(cs0, 32);
      const unsigned int es1 = __shfl_xor(cs1, 32);
      const unsigned int es2 = __shfl_xor(cs2, 32);
      const unsigned int es3 = __shfl_xor(cs3, 32);
      const unsigned int es4 = __shfl_xor(cs4, 32);
      const unsigned int es5 = __shfl_xor(cs5, 32);
      const unsigned int es6 = __shfl_xor(cs6, 32);
      const unsigned int es7 = __shfl_xor(cs7, 32);
      union { unsigned int u[4]; bf16x8 v; } paE, paO;
      paE.u[0] = hi ? es2 : cs0;
      paE.u[1] = hi ? es3 : cs1;
      paE.u[2] = hi ? cs2 : es0;
      paE.u[3] = hi ? cs3 : es1;
      paO.u[0] = hi ? es6 : cs4;
      paO.u[1] = hi ? es7 : cs5;
      paO.u[2] = hi ? cs6 : es4;
      paO.u[3] = hi ? cs7 : es5;
#pragma unroll
      for (int nt = 0; nt < 2; ++nt) {
        const int vrow = nt * 32 + lq;
        const int vsw = ((vrow & 7) ^ ((vrow >> 3) & 7)) << 4;
        bf16x8 vbE = *(const bf16x8*)((const char*)Vt +
            (vrow * 128 + (((kt * 64) + hi * 16) ^ vsw)));
        oacc[nt] = __builtin_amdgcn_mfma_f32_32x32x16_bf16(paE.v, vbE, oacc[nt], 0, 0, 0);
        bf16x8 vbO = *(const bf16x8*)((const char*)Vt +
            (vrow * 128 + (((kt * 64 + 32) + hi * 16) ^ vsw)));
        oacc[nt] = __builtin_amdgcn_mfma_f32_32x32x16_bf16(paO.v, vbO, oacc[nt], 0, 0, 0);
      }
    }
  }

  // ---- epilogue: O[q][d] /= lsum[q]; store bf16 ----
  const float inv = 1.0f / lsum;
#pragma unroll
  for (int r = 0; r < 16; ++r) {
    const int crow = (r & 3) + 8 * (r >> 2) + 4 * hi;
    const float ir = __shfl(inv, crow);
    const long orow = (long)b * 2048 + qw0 + crow;
#pragma unroll
    for (int nt = 0; nt < 2; ++nt)
      Oout[orow * 1024 + h * 64 + nt * 32 + lq] = __float2bfloat16(oacc[nt][r] * ir);
  }
}

extern "C" void kernel_launch(void* const* d_in, const int* in_sizes, int n_in,
                              void* d_out, int out_size, void* d_ws, size_t ws_size,
                              hipStream_t stream) {
  const float* X = (const float*)d_in[0];
  const int* pmask = (const int*)d_in[1];
  const float* W_Q = (const float*)d_in[2];
  const float* W_K = (const float*)d_in[3];
  const float* W_V = (const float*)d_in[4];
  const float* W_O = (const float*)d_in[5];
  const float* g1 = (const float*)d_in[6];
  const float* b1 = (const float*)d_in[7];
  const float* W1 = (const float*)d_in[8];
  const float* bias1 = (const float*)d_in[9];
  const float* W2 = (const float*)d_in[10];
  const float* bias2 = (const float*)d_in[11];
  const float* g2 = (const float*)d_in[12];
  const float* b2 = (const float*)d_in[13];
  (void)in_sizes; (void)n_in; (void)out_size; (void)ws_size;

  char* ws = (char*)d_ws;
  const size_t MB = 1ull << 20;
  // workspace layout (80 MB total), ff1 overlaps dead QKV+attn:
  bf16* Wqkv_t = (bf16*)(ws + 0);         // 3072 x 1024   (6 MB)
  bf16* Wo_t   = (bf16*)(ws + 6 * MB);    // 1024 x 1024   (2 MB)
  bf16* W1_t   = (bf16*)(ws + 8 * MB);    // 4096 x 1024   (8 MB)
  bf16* W2_t   = (bf16*)(ws + 16 * MB);   // 1024 x 4096   (8 MB)
  bf16* xn     = (bf16*)(ws + 24 * MB);   // 4096 x 1024   (8 MB, reused as nn2)
  bf16* QKV    = (bf16*)(ws + 32 * MB);   // 4096 x 3072   (24 MB)
  bf16* attnb  = (bf16*)(ws + 56 * MB);   // 4096 x 1024   (8 MB)
  float* res1  = (float*)(ws + 64 * MB);  // 4096 x 1024 f32 (16 MB)
  bf16* ff1    = (bf16*)(ws + 32 * MB);   // 4096 x 4096   (32 MB) over QKV+attnb

  // weight convert + transpose (f32 KxN -> bf16 NxK)
  transpose_to_bf16<<<dim3(32, 32), 256, 0, stream>>>(W_Q, Wqkv_t, 1024, 1024);
  transpose_to_bf16<<<dim3(32, 32), 256, 0, stream>>>(W_K, Wqkv_t + (size_t)1024 * 1024, 1024, 1024);
  transpose_to_bf16<<<dim3(32, 32), 256, 0, stream>>>(W_V, Wqkv_t + (size_t)2048 * 1024, 1024, 1024);
  transpose_to_bf16<<<dim3(32, 32), 256, 0, stream>>>(W_O, Wo_t, 1024, 1024);
  transpose_to_bf16<<<dim3(128, 32), 256, 0, stream>>>(W1, W1_t, 1024, 4096);
  transpose_to_bf16<<<dim3(32, 128), 256, 0, stream>>>(W2, W2_t, 4096, 1024);

  // LN1
  ln_kernel<<<4096, 256, 0, stream>>>(X, g1, b1, xn);
  // fused QKV projection
  gemm_bt<0><<<32 * 24, 256, 0, stream>>>(xn, Wqkv_t, 4096, 3072, 1024, nullptr, nullptr, QKV);
  // attention (swapped-QK^T structure)
  attn_kernel<<<dim3(16, 32), 256, 0, stream>>>(QKV, pmask, attnb);
  // O projection + residual (f32)
  gemm_bt<1><<<32 * 8, 256, 0, stream>>>(attnb, Wo_t, 4096, 1024, 1024, nullptr, X, res1);
  // LN2
  ln_kernel<<<4096, 256, 0, stream>>>(res1, g2, b2, xn);
  // FF1 + bias + exact GELU
  gemm_bt<2><<<32 * 32, 256, 0, stream>>>(xn, W1_t, 4096, 4096, 1024, bias1, nullptr, ff1);
  // FF2 + bias + residual -> final f32 output
  gemm_bt<3><<<32 * 8, 256, 0, stream>>>(ff1, W2_t, 4096, 1024, 4096, bias2, res1, (float*)d_out);
}

// Round 4
// 347.355 us; speedup vs baseline: 1.2967x; 1.0787x over previous
//
#include <hip/hip_runtime.h>
#include <hip/hip_bf16.h>

// EncoderLayer on MI355X (gfx950).
// B=2, S=2048, D=1024, H=16, DK=64. M = B*S = 4096.
// R4 (bisect of R3 failure): attention keeps async-K staging (global_load_lds,
// pre-swizzled source), double-buffered LDS with ONE barrier per kv-tile, and
// T14 split V staging (global->reg loads issued at loop top, ds_write scatter
// after PV). V tr-read REVERTED to R2's proven scatter+ds_read_b128 path.
// Softmax reverted to 0.125 prescale + __expf (bit-identical to passing R2).
// GEMMs: m97 structure + XCD-aware blockIdx swizzle.

using bf16 = __hip_bfloat16;
typedef __attribute__((ext_vector_type(4))) float f32x4;
typedef __attribute__((ext_vector_type(16))) float f32x16;
typedef __attribute__((ext_vector_type(8))) short bf16x8;

#define DEVI static __device__ __forceinline__

DEVI void async_copy16(const void* g, void* l) {
  __builtin_amdgcn_global_load_lds(
      (const __attribute__((address_space(1))) void*)g,
      (__attribute__((address_space(3))) void*)l, 16, 0, 0);
}

DEVI ushort f2bf_bits(float v) {
  __hip_bfloat16 h = __float2bfloat16(v);
  return *reinterpret_cast<ushort*>(&h);
}

DEVI float bfbits2f(ushort u) {
  union { float f; unsigned int i; } x;
  x.i = ((unsigned int)u) << 16;
  return x.f;
}

DEVI unsigned int pk2(float lo, float hi) {
  return (unsigned int)f2bf_bits(lo) | ((unsigned int)f2bf_bits(hi) << 16);
}

// ---------------- LayerNorm: f32 in (rows x 1024) -> bf16 out ----------------
__global__ __launch_bounds__(256) void ln_kernel(
    const float* __restrict__ in, const float* __restrict__ gamma,
    const float* __restrict__ beta, bf16* __restrict__ out) {
  const long row = blockIdx.x;
  const int t = threadIdx.x;
  float4 x = ((const float4*)(in + row * 1024))[t];
  float s = x.x + x.y + x.z + x.w;
  float s2 = x.x * x.x + x.y * x.y + x.z * x.z + x.w * x.w;
#pragma unroll
  for (int m = 1; m < 64; m <<= 1) {
    s += __shfl_xor(s, m);
    s2 += __shfl_xor(s2, m);
  }
  __shared__ float red[8];
  const int w = t >> 6, l = t & 63;
  if (l == 0) { red[w] = s; red[4 + w] = s2; }
  __syncthreads();
  s = red[0] + red[1] + red[2] + red[3];
  s2 = red[4] + red[5] + red[6] + red[7];
  const float mean = s * (1.0f / 1024.0f);
  const float var = s2 * (1.0f / 1024.0f) - mean * mean;
  const float rstd = rsqrtf(var + 1e-6f);
  float4 g4 = ((const float4*)gamma)[t];
  float4 b4 = ((const float4*)beta)[t];
  union { ushort h[4]; uint2 u; } o;
  o.h[0] = f2bf_bits(g4.x * (x.x - mean) * rstd + b4.x);
  o.h[1] = f2bf_bits(g4.y * (x.y - mean) * rstd + b4.y);
  o.h[2] = f2bf_bits(g4.z * (x.z - mean) * rstd + b4.z);
  o.h[3] = f2bf_bits(g4.w * (x.w - mean) * rstd + b4.w);
  ((uint2*)(out + row * 1024))[t] = o.u;
}

// ------------- transpose f32 (K x N) -> bf16 (N x K), 32x32 tiles -------------
__global__ __launch_bounds__(256) void transpose_to_bf16(
    const float* __restrict__ W, bf16* __restrict__ Wt, const int K, const int N) {
  __shared__ float tile[32][33];
  const int tx = threadIdx.x & 31, ty = threadIdx.x >> 5;  // 32 x 8
  const int n0 = blockIdx.x << 5, k0 = blockIdx.y << 5;
#pragma unroll
  for (int i = 0; i < 32; i += 8)
    tile[ty + i][tx] = W[(long)(k0 + ty + i) * N + n0 + tx];
  __syncthreads();
#pragma unroll
  for (int i = 0; i < 32; i += 8)
    Wt[(long)(n0 + ty + i) * K + k0 + tx] = __float2bfloat16(tile[tx][ty + i]);
}

// ---------------- GEMM: C(MxN) = A(MxK,bf16) * Bt(NxK,bf16)^T ----------------
// 128x128 tile, BK=32, 4 waves, global_load_lds staging (m97 structure).
// XCD-aware blockIdx swizzle (all grids %8==0 -> bijective).
template <int EPI>
__global__ __launch_bounds__(256) void gemm_bt(
    const bf16* __restrict__ A, const bf16* __restrict__ Bt,
    const int M, const int N, const int K,
    const float* __restrict__ bias, const float* __restrict__ res,
    void* __restrict__ Cout) {
  __shared__ bf16 As[128 * 32];
  __shared__ bf16 Bs[128 * 32];
  const int t = threadIdx.x;
  const int w = t >> 6, l = t & 63;
  const int nb = N >> 7;
  const int cpx = gridDim.x >> 3;
  const int bidx = (blockIdx.x & 7) * cpx + (blockIdx.x >> 3);
  const int bm = bidx / nb, bn = bidx % nb;
  const long row0 = (long)bm << 7, col0 = (long)bn << 7;
  const int wr = (w >> 1) << 6, wc = (w & 1) << 6;
  const int lr = l & 15, lk = (l >> 4) << 3;

  f32x4 acc[4][4];
#pragma unroll
  for (int m = 0; m < 4; ++m)
#pragma unroll
    for (int n = 0; n < 4; ++n) acc[m][n] = (f32x4){0.f, 0.f, 0.f, 0.f};

  const bf16* gA = A + (row0 + (t >> 2)) * K + ((t & 3) << 3);
  const bf16* gB = Bt + (col0 + (t >> 2)) * K + ((t & 3) << 3);
  char* lA = (char*)As + (w << 10);
  char* lB = (char*)Bs + (w << 10);
  const long k64 = (long)64 * K;

  for (int k0 = 0; k0 < K; k0 += 32) {
    __syncthreads();
    async_copy16(gA + k0, lA);
    async_copy16(gA + k64 + k0, lA + 4096);
    async_copy16(gB + k0, lB);
    async_copy16(gB + k64 + k0, lB + 4096);
    __syncthreads();
    bf16x8 af[4], bfr[4];
#pragma unroll
    for (int m = 0; m < 4; ++m)
      af[m] = *(const bf16x8*)&As[(wr + m * 16 + lr) * 32 + lk];
#pragma unroll
    for (int n = 0; n < 4; ++n)
      bfr[n] = *(const bf16x8*)&Bs[(wc + n * 16 + lr) * 32 + lk];
#pragma unroll
    for (int m = 0; m < 4; ++m)
#pragma unroll
      for (int n = 0; n < 4; ++n)
        acc[m][n] = __builtin_amdgcn_mfma_f32_16x16x32_bf16(af[m], bfr[n], acc[m][n], 0, 0, 0);
  }

  bf16* Cb = (bf16*)Cout;
  float* Cf = (float*)Cout;
#pragma unroll
  for (int m = 0; m < 4; ++m) {
#pragma unroll
    for (int r = 0; r < 4; ++r) {
      const long crow = row0 + wr + m * 16 + ((l >> 4) << 2) + r;
      const long rbase = crow * N;
#pragma unroll
      for (int n = 0; n < 4; ++n) {
        const long ccol = col0 + wc + n * 16 + lr;
        float v = acc[m][n][r];
        if (EPI == 2) {
          v += bias[ccol];
          v = 0.5f * v * (1.0f + erff(v * 0.70710678118654752f));
        }
        if (EPI == 3) v += bias[ccol] + res[rbase + ccol];
        if (EPI == 1) v += res[rbase + ccol];
        if (EPI == 0 || EPI == 2)
          Cb[rbase + ccol] = __float2bfloat16(v);
        else
          Cf[rbase + ccol] = v;
      }
    }
  }
}

// ---------------- flash attention (swapped QK^T, async-K, dbuf, T14 V) -------
// Grid: x = S/128 q-tiles, y = B*H. Block 256 = 4 waves; wave w owns q rows
// [w*32, w*32+32). KVBLK=64 per tile, double-buffered, ONE barrier per tile.
// LDS: [0,16K) K dbuf (row-major, chunk-swizzled, staged via global_load_lds
//              with pre-swizzled source); [16K,32K) V^T dbuf (R2 scatter layout,
//              byte ^= ((d&7)^((d>>3)&7))<<4, staged global->reg->ds_write).
__global__ __launch_bounds__(256) void attn_kernel(
    const bf16* __restrict__ QKV, const int* __restrict__ pmask,
    bf16* __restrict__ Oout) {
  const int bh = blockIdx.y;
  const int b = bh >> 4, h = bh & 15;
  const int q0 = blockIdx.x << 7;
  const int t = threadIdx.x;
  const int w = t >> 6, l = t & 63;
  const int lq = l & 31, hi = l >> 5;

  __shared__ __align__(16) char smem[32768];

  const long base = (long)b * 2048 * 3072;
  const bf16* Qg = QKV + base + h * 64;
  const bf16* Kg = QKV + base + 1024 + h * 64;
  const bf16* Vg = QKV + base + 2048 + h * 64;

  // K staging source offsets (pre-swizzled; LDS dest linear, chunk c = w*128+p*64+l)
  int kSrc[2];
#pragma unroll
  for (int p = 0; p < 2; ++p) {
    const int r = w * 16 + p * 8 + (l >> 3);
    kSrc[p] = r * 3072 + (((l & 7) ^ (r & 7)) << 3);
  }
  // V staging coords (R2 scatter): chunk c = p*256 + t -> row vr, chunk vsg
  const int vr0 = t >> 3, vsg = t & 7;  // p adds 32 rows

  // ---- Q fragments in registers, prescaled by 1/8 (exact) ----
  const int qw0 = q0 + w * 32;
  bf16x8 qf[4];
#pragma unroll
  for (int dc = 0; dc < 4; ++dc) {
    uint4 raw = *(const uint4*)(Qg + (long)(qw0 + lq) * 3072 + dc * 16 + hi * 8);
    union { uint4 u4; ushort us[8]; } in; in.u4 = raw;
    union { bf16x8 v; ushort us[8]; } o;
#pragma unroll
    for (int e = 0; e < 8; ++e) o.us[e] = f2bf_bits(0.125f * bfbits2f(in.us[e]));
    qf[dc] = o.v;
  }

  // mask rank-1 MFMA B-operand: B[0][q] = 1
  union { unsigned int u[4]; bf16x8 v; } bones;
  bones.u[0] = (hi == 0) ? 0x00003F80u : 0u;
  bones.u[1] = bones.u[2] = bones.u[3] = 0u;

  // ---- prologue: stage tile 0 ----
  uint4 vreg[2];
#pragma unroll
  for (int p = 0; p < 2; ++p) {
    vreg[p] = *(const uint4*)(Vg + (long)(p * 32 + vr0) * 3072 + vsg * 8);
    async_copy16(Kg + kSrc[p], smem + w * 2048 + p * 1024);
  }
#pragma unroll
  for (int p = 0; p < 2; ++p) {
    const int r = p * 32 + vr0;
    const ushort* vs = (const ushort*)&vreg[p];
#pragma unroll
    for (int e = 0; e < 8; ++e) {
      const int d = vsg * 8 + e;
      *(ushort*)(smem + 16384 + d * 128 + ((r * 2) ^ (((e ^ vsg) & 7) << 4))) = vs[e];
    }
  }

  f32x16 oacc[2];
#pragma unroll
  for (int nt = 0; nt < 2; ++nt)
#pragma unroll
    for (int r = 0; r < 16; ++r) oacc[nt][r] = 0.f;
  float mrun = -3.0e38f, lsum = 0.f;
  int cur = 0;

  __syncthreads();  // tile 0 staged (vmcnt+lgkmcnt drained by barrier)

  for (int ktg = 0; ktg < 32; ++ktg) {
    // ---- issue next tile's loads early (T14): V->regs, K->LDS(other buf) ----
    if (ktg < 31) {
      const long nrow0 = (long)(ktg + 1) * 64 * 3072;
#pragma unroll
      for (int p = 0; p < 2; ++p) {
        vreg[p] = *(const uint4*)(Vg + nrow0 + (long)(p * 32 + vr0) * 3072 + vsg * 8);
        async_copy16(Kg + nrow0 + kSrc[p], smem + (cur ^ 1) * 8192 + w * 2048 + p * 1024);
      }
    }
    const int k0 = ktg << 6;
    const char* Ks = smem + cur * 8192;
    const char* Vt = smem + 16384 + cur * 8192;

    // ---- S^T = K Q^T : lane holds S^T[k = kt*32 + crow(r,hi)][q = lq] ----
    f32x16 sacc[2];
#pragma unroll
    for (int kt = 0; kt < 2; ++kt) {
#pragma unroll
      for (int r = 0; r < 16; ++r) sacc[kt][r] = 0.f;
#pragma unroll
      for (int dc = 0; dc < 4; ++dc) {
        bf16x8 ka = *(const bf16x8*)(Ks +
            ((kt * 32 + lq) * 128 + ((dc * 32 + hi * 16) ^ ((lq & 7) << 4))));
        sacc[kt] = __builtin_amdgcn_mfma_f32_32x32x16_bf16(ka, qf[dc], sacc[kt], 0, 0, 0);
      }
      const int mv = pmask[b * 2048 + k0 + kt * 32 + lq];
      union { unsigned int u[4]; bf16x8 v; } aadd;
      aadd.u[0] = (hi == 0 && mv == 0) ? (unsigned int)f2bf_bits(-1.0e9f) : 0u;
      aadd.u[1] = aadd.u[2] = aadd.u[3] = 0u;
      sacc[kt] = __builtin_amdgcn_mfma_f32_32x32x16_bf16(aadd.v, bones.v, sacc[kt], 0, 0, 0);
    }

    // ---- online softmax; lane pair (l, l^32) shares column lq ----
    float tmax = -3.0e38f;
#pragma unroll
    for (int kt = 0; kt < 2; ++kt)
#pragma unroll
      for (int r = 0; r < 16; ++r) tmax = fmaxf(tmax, sacc[kt][r]);
    tmax = fmaxf(tmax, __shfl_xor(tmax, 32));
    const bool need = (bool)__any(tmax > mrun);
    const float mnew = need ? fmaxf(mrun, tmax) : mrun;
    float psum = 0.f;
#pragma unroll
    for (int kt = 0; kt < 2; ++kt)
#pragma unroll
      for (int r = 0; r < 16; ++r) {
        const float p = __expf(sacc[kt][r] - mnew);
        sacc[kt][r] = p;
        psum += p;
      }
    psum += __shfl_xor(psum, 32);
    if (need) {
      const float alpha = __expf(mrun - mnew);
      mrun = mnew;
      lsum = lsum * alpha + psum;
#pragma unroll
      for (int r = 0; r < 16; ++r) {
        const float ar = __shfl(alpha, (r & 3) + 8 * (r >> 2) + 4 * hi);
        oacc[0][r] *= ar;
        oacc[1][r] *= ar;
      }
    } else {
      lsum += psum;
    }

    // ---- P -> bf16 A-fragments via pack + lane^32 exchange ----
    union { unsigned int u[4]; bf16x8 v; } paE[2], paO[2];
#pragma unroll
    for (int kt = 0; kt < 2; ++kt) {
      const unsigned int cs0 = pk2(sacc[kt][0], sacc[kt][1]);
      const unsigned int cs1 = pk2(sacc[kt][2], sacc[kt][3]);
      const unsigned int cs2 = pk2(sacc[kt][4], sacc[kt][5]);
      const unsigned int cs3 = pk2(sacc[kt][6], sacc[kt][7]);
      const unsigned int cs4 = pk2(sacc[kt][8], sacc[kt][9]);
      const unsigned int cs5 = pk2(sacc[kt][10], sacc[kt][11]);
      const unsigned int cs6 = pk2(sacc[kt][12], sacc[kt][13]);
      const unsigned int cs7 = pk2(sacc[kt][14], sacc[kt][15]);
      const unsigned int es0 = __shfl_xor(cs0, 32);
      const unsigned int es1 = __shfl_xor(cs1, 32);
      const unsigned int es2 = __shfl_xor(cs2, 32);
      const unsigned int es3 = __shfl_xor(cs3, 32);
      const unsigned int es4 = __shfl_xor(cs4, 32);
      const unsigned int es5 = __shfl_xor(cs5, 32);
      const unsigned int es6 = __shfl_xor(cs6, 32);
      const unsigned int es7 = __shfl_xor(cs7, 32);
      paE[kt].u[0] = hi ? es2 : cs0;
      paE[kt].u[1] = hi ? es3 : cs1;
      paE[kt].u[2] = hi ? cs2 : es0;
      paE[kt].u[3] = hi ? cs3 : es1;
      paO[kt].u[0] = hi ? es6 : cs4;
      paO[kt].u[1] = hi ? es7 : cs5;
      paO[kt].u[2] = hi ? cs6 : es4;
      paO[kt].u[3] = hi ? cs7 : es5;
    }

    // ---- O += P V (V^T rows from LDS, R2-proven addressing) ----
#pragma unroll
    for (int kt = 0; kt < 2; ++kt)
#pragma unroll
      for (int nt = 0; nt < 2; ++nt) {
        const int vrow = nt * 32 + lq;
        const int vsw = ((vrow & 7) ^ ((vrow >> 3) & 7)) << 4;
        bf16x8 vbE = *(const bf16x8*)(Vt + (vrow * 128 + ((kt * 64 + hi * 16) ^ vsw)));
        oacc[nt] = __builtin_amdgcn_mfma_f32_32x32x16_bf16(paE[kt].v, vbE, oacc[nt], 0, 0, 0);
        bf16x8 vbO = *(const bf16x8*)(Vt + (vrow * 128 + ((kt * 64 + 32 + hi * 16) ^ vsw)));
        oacc[nt] = __builtin_amdgcn_mfma_f32_32x32x16_bf16(paO[kt].v, vbO, oacc[nt], 0, 0, 0);
      }

    // ---- late half of T14: scatter V-next regs into the other buffer ----
    if (ktg < 31) {
      char* VtN = smem + 16384 + (cur ^ 1) * 8192;
#pragma unroll
      for (int p = 0; p < 2; ++p) {
        const int r = p * 32 + vr0;
        const ushort* vs = (const ushort*)&vreg[p];
#pragma unroll
        for (int e = 0; e < 8; ++e) {
          const int d = vsg * 8 + e;
          *(ushort*)(VtN + d * 128 + ((r * 2) ^ (((e ^ vsg) & 7) << 4))) = vs[e];
        }
      }
    }

    __syncthreads();  // publish next buffer (vmcnt+lgkmcnt drain) / free cur
    cur ^= 1;
  }

  // ---- epilogue: O[q][d] /= lsum[q]; store bf16 ----
  const float inv = 1.0f / lsum;
#pragma unroll
  for (int r = 0; r < 16; ++r) {
    const int crow = (r & 3) + 8 * (r >> 2) + 4 * hi;
    const float ir = __shfl(inv, crow);
    const long orow = (long)b * 2048 + qw0 + crow;
#pragma unroll
    for (int nt = 0; nt < 2; ++nt)
      Oout[orow * 1024 + h * 64 + nt * 32 + lq] = __float2bfloat16(oacc[nt][r] * ir);
  }
}

extern "C" void kernel_launch(void* const* d_in, const int* in_sizes, int n_in,
                              void* d_out, int out_size, void* d_ws, size_t ws_size,
                              hipStream_t stream) {
  const float* X = (const float*)d_in[0];
  const int* pmask = (const int*)d_in[1];
  const float* W_Q = (const float*)d_in[2];
  const float* W_K = (const float*)d_in[3];
  const float* W_V = (const float*)d_in[4];
  const float* W_O = (const float*)d_in[5];
  const float* g1 = (const float*)d_in[6];
  const float* b1 = (const float*)d_in[7];
  const float* W1 = (const float*)d_in[8];
  const float* bias1 = (const float*)d_in[9];
  const float* W2 = (const float*)d_in[10];
  const float* bias2 = (const float*)d_in[11];
  const float* g2 = (const float*)d_in[12];
  const float* b2 = (const float*)d_in[13];
  (void)in_sizes; (void)n_in; (void)out_size; (void)ws_size;

  char* ws = (char*)d_ws;
  const size_t MB = 1ull << 20;
  bf16* Wqkv_t = (bf16*)(ws + 0);         // 3072 x 1024   (6 MB)
  bf16* Wo_t   = (bf16*)(ws + 6 * MB);    // 1024 x 1024   (2 MB)
  bf16* W1_t   = (bf16*)(ws + 8 * MB);    // 4096 x 1024   (8 MB)
  bf16* W2_t   = (bf16*)(ws + 16 * MB);   // 1024 x 4096   (8 MB)
  bf16* xn     = (bf16*)(ws + 24 * MB);   // 4096 x 1024   (8 MB, reused as nn2)
  bf16* QKV    = (bf16*)(ws + 32 * MB);   // 4096 x 3072   (24 MB)
  bf16* attnb  = (bf16*)(ws + 56 * MB);   // 4096 x 1024   (8 MB)
  float* res1  = (float*)(ws + 64 * MB);  // 4096 x 1024 f32 (16 MB)
  bf16* ff1    = (bf16*)(ws + 32 * MB);   // 4096 x 4096   (32 MB) over QKV+attnb

  transpose_to_bf16<<<dim3(32, 32), 256, 0, stream>>>(W_Q, Wqkv_t, 1024, 1024);
  transpose_to_bf16<<<dim3(32, 32), 256, 0, stream>>>(W_K, Wqkv_t + (size_t)1024 * 1024, 1024, 1024);
  transpose_to_bf16<<<dim3(32, 32), 256, 0, stream>>>(W_V, Wqkv_t + (size_t)2048 * 1024, 1024, 1024);
  transpose_to_bf16<<<dim3(32, 32), 256, 0, stream>>>(W_O, Wo_t, 1024, 1024);
  transpose_to_bf16<<<dim3(128, 32), 256, 0, stream>>>(W1, W1_t, 1024, 4096);
  transpose_to_bf16<<<dim3(32, 128), 256, 0, stream>>>(W2, W2_t, 4096, 1024);

  ln_kernel<<<4096, 256, 0, stream>>>(X, g1, b1, xn);
  gemm_bt<0><<<32 * 24, 256, 0, stream>>>(xn, Wqkv_t, 4096, 3072, 1024, nullptr, nullptr, QKV);
  attn_kernel<<<dim3(16, 32), 256, 0, stream>>>(QKV, pmask, attnb);
  gemm_bt<1><<<32 * 8, 256, 0, stream>>>(attnb, Wo_t, 4096, 1024, 1024, nullptr, X, res1);
  ln_kernel<<<4096, 256, 0, stream>>>(res1, g2, b2, xn);
  gemm_bt<2><<<32 * 32, 256, 0, stream>>>(xn, W1_t, 4096, 4096, 1024, bias1, nullptr, ff1);
  gemm_bt<3><<<32 * 8, 256, 0, stream>>>(ff1, W2_t, 4096, 1024, 4096, bias2, res1, (float*)d_out);
}

// Round 5
// 322.653 us; speedup vs baseline: 1.3960x; 1.0766x over previous
//
#include <hip/hip_runtime.h>
#include <hip/hip_bf16.h>

// EncoderLayer on MI355X (gfx950).
// B=2, S=2048, D=1024, H=16, DK=64. M = B*S = 4096.
// R5: FF2 split-K=2 (one 512-block dispatch -> 2 blocks/CU) + reduce kernel;
//     d_out doubles as the post-attention residual buffer (frees 16MB so both
//     f32 partials fit in 80MB ws); attn softmax in base-2 (exp2f, Q prescaled
//     by log2(e)/8) with T13 defer-rescale threshold (8); QKVO weight
//     transposes merged into one grid.z=4 dispatch.

using bf16 = __hip_bfloat16;
typedef __attribute__((ext_vector_type(4))) float f32x4;
typedef __attribute__((ext_vector_type(16))) float f32x16;
typedef __attribute__((ext_vector_type(8))) short bf16x8;

#define DEVI static __device__ __forceinline__

DEVI void async_copy16(const void* g, void* l) {
  __builtin_amdgcn_global_load_lds(
      (const __attribute__((address_space(1))) void*)g,
      (__attribute__((address_space(3))) void*)l, 16, 0, 0);
}

DEVI ushort f2bf_bits(float v) {
  __hip_bfloat16 h = __float2bfloat16(v);
  return *reinterpret_cast<ushort*>(&h);
}

DEVI float bfbits2f(ushort u) {
  union { float f; unsigned int i; } x;
  x.i = ((unsigned int)u) << 16;
  return x.f;
}

DEVI unsigned int pk2(float lo, float hi) {
  return (unsigned int)f2bf_bits(lo) | ((unsigned int)f2bf_bits(hi) << 16);
}

// ---------------- LayerNorm: f32 in (rows x 1024) -> bf16 out ----------------
__global__ __launch_bounds__(256) void ln_kernel(
    const float* __restrict__ in, const float* __restrict__ gamma,
    const float* __restrict__ beta, bf16* __restrict__ out) {
  const long row = blockIdx.x;
  const int t = threadIdx.x;
  float4 x = ((const float4*)(in + row * 1024))[t];
  float s = x.x + x.y + x.z + x.w;
  float s2 = x.x * x.x + x.y * x.y + x.z * x.z + x.w * x.w;
#pragma unroll
  for (int m = 1; m < 64; m <<= 1) {
    s += __shfl_xor(s, m);
    s2 += __shfl_xor(s2, m);
  }
  __shared__ float red[8];
  const int w = t >> 6, l = t & 63;
  if (l == 0) { red[w] = s; red[4 + w] = s2; }
  __syncthreads();
  s = red[0] + red[1] + red[2] + red[3];
  s2 = red[4] + red[5] + red[6] + red[7];
  const float mean = s * (1.0f / 1024.0f);
  const float var = s2 * (1.0f / 1024.0f) - mean * mean;
  const float rstd = rsqrtf(var + 1e-6f);
  float4 g4 = ((const float4*)gamma)[t];
  float4 b4 = ((const float4*)beta)[t];
  union { ushort h[4]; uint2 u; } o;
  o.h[0] = f2bf_bits(g4.x * (x.x - mean) * rstd + b4.x);
  o.h[1] = f2bf_bits(g4.y * (x.y - mean) * rstd + b4.y);
  o.h[2] = f2bf_bits(g4.z * (x.z - mean) * rstd + b4.z);
  o.h[3] = f2bf_bits(g4.w * (x.w - mean) * rstd + b4.w);
  ((uint2*)(out + row * 1024))[t] = o.u;
}

// ------------- transpose f32 (K x N) -> bf16 (N x K), 32x32 tiles -------------
__global__ __launch_bounds__(256) void transpose_to_bf16(
    const float* __restrict__ W, bf16* __restrict__ Wt, const int K, const int N) {
  __shared__ float tile[32][33];
  const int tx = threadIdx.x & 31, ty = threadIdx.x >> 5;
  const int n0 = blockIdx.x << 5, k0 = blockIdx.y << 5;
#pragma unroll
  for (int i = 0; i < 32; i += 8)
    tile[ty + i][tx] = W[(long)(k0 + ty + i) * N + n0 + tx];
  __syncthreads();
#pragma unroll
  for (int i = 0; i < 32; i += 8)
    Wt[(long)(n0 + ty + i) * K + k0 + tx] = __float2bfloat16(tile[tx][ty + i]);
}

// merged Q/K/V/O weight transpose (all 1024x1024), z selects source.
__global__ __launch_bounds__(256) void transpose_qkvo(
    const float* __restrict__ q, const float* __restrict__ k,
    const float* __restrict__ v, const float* __restrict__ o,
    bf16* __restrict__ dst) {
  const float* W = (blockIdx.z == 0) ? q : (blockIdx.z == 1) ? k
                   : (blockIdx.z == 2) ? v : o;
  bf16* Wt = dst + (size_t)blockIdx.z * 1024 * 1024;
  __shared__ float tile[32][33];
  const int tx = threadIdx.x & 31, ty = threadIdx.x >> 5;
  const int n0 = blockIdx.x << 5, k0 = blockIdx.y << 5;
#pragma unroll
  for (int i = 0; i < 32; i += 8)
    tile[ty + i][tx] = W[(long)(k0 + ty + i) * 1024 + n0 + tx];
  __syncthreads();
#pragma unroll
  for (int i = 0; i < 32; i += 8)
    Wt[(long)(n0 + ty + i) * 1024 + k0 + tx] = __float2bfloat16(tile[tx][ty + i]);
}

// ---------------- GEMM: C(MxN) = A(MxK,bf16) * Bt(NxK,bf16)^T ----------------
// 128x128 tile, BK=32, 4 waves, global_load_lds staging (m97 structure),
// XCD-aware bijective blockIdx swizzle. lda/ldb = row strides (for split-K).
// KSPLIT=2: grid doubled; slice sl in {0,1} reads K-cols [sl*K,(sl+1)*K) and
// stores raw f32 into (sl==0 ? Cout : (float*)bias2ptr).
// EPI: 0 = store bf16; 1 = +res(f32) store f32; 2 = +bias, exact GELU, bf16;
//      4 = raw f32 partial store (split-K; 'pother' is slice-1 base).
template <int EPI, int KSPLIT>
__global__ __launch_bounds__(256) void gemm_bt(
    const bf16* __restrict__ A, const bf16* __restrict__ Bt,
    const int M, const int N, const int K, const int lda, const int ldb,
    const float* __restrict__ bias, const float* __restrict__ res,
    float* __restrict__ pother, void* __restrict__ Cout) {
  __shared__ bf16 As[128 * 32];
  __shared__ bf16 Bs[128 * 32];
  const int t = threadIdx.x;
  const int w = t >> 6, l = t & 63;
  const int nb = N >> 7;
  const int cpx = gridDim.x >> 3;
  int bidx = (blockIdx.x & 7) * cpx + (blockIdx.x >> 3);
  int sl = 0;
  if (KSPLIT == 2) {
    const int half = gridDim.x >> 1;
    sl = bidx >= half;
    bidx -= sl * half;
  }
  const int bm = bidx / nb, bn = bidx % nb;
  const long row0 = (long)bm << 7, col0 = (long)bn << 7;
  const int wr = (w >> 1) << 6, wc = (w & 1) << 6;
  const int lr = l & 15, lk = (l >> 4) << 3;

  f32x4 acc[4][4];
#pragma unroll
  for (int m = 0; m < 4; ++m)
#pragma unroll
    for (int n = 0; n < 4; ++n) acc[m][n] = (f32x4){0.f, 0.f, 0.f, 0.f};

  const bf16* gA = A + (row0 + (t >> 2)) * (long)lda + (long)sl * K + ((t & 3) << 3);
  const bf16* gB = Bt + (col0 + (t >> 2)) * (long)ldb + (long)sl * K + ((t & 3) << 3);
  char* lA = (char*)As + (w << 10);
  char* lB = (char*)Bs + (w << 10);
  const long k64a = (long)64 * lda, k64b = (long)64 * ldb;

  for (int k0 = 0; k0 < K; k0 += 32) {
    __syncthreads();
    async_copy16(gA + k0, lA);
    async_copy16(gA + k64a + k0, lA + 4096);
    async_copy16(gB + k0, lB);
    async_copy16(gB + k64b + k0, lB + 4096);
    __syncthreads();
    bf16x8 af[4], bfr[4];
#pragma unroll
    for (int m = 0; m < 4; ++m)
      af[m] = *(const bf16x8*)&As[(wr + m * 16 + lr) * 32 + lk];
#pragma unroll
    for (int n = 0; n < 4; ++n)
      bfr[n] = *(const bf16x8*)&Bs[(wc + n * 16 + lr) * 32 + lk];
#pragma unroll
    for (int m = 0; m < 4; ++m)
#pragma unroll
      for (int n = 0; n < 4; ++n)
        acc[m][n] = __builtin_amdgcn_mfma_f32_16x16x32_bf16(af[m], bfr[n], acc[m][n], 0, 0, 0);
  }

  bf16* Cb = (bf16*)Cout;
  float* Cf = (float*)Cout;
  if (EPI == 4 && sl == 1) Cf = pother;
#pragma unroll
  for (int m = 0; m < 4; ++m) {
#pragma unroll
    for (int r = 0; r < 4; ++r) {
      const long crow = row0 + wr + m * 16 + ((l >> 4) << 2) + r;
      const long rbase = crow * N;
#pragma unroll
      for (int n = 0; n < 4; ++n) {
        const long ccol = col0 + wc + n * 16 + lr;
        float v = acc[m][n][r];
        if (EPI == 2) {
          v += bias[ccol];
          v = 0.5f * v * (1.0f + erff(v * 0.70710678118654752f));
        }
        if (EPI == 1) v += res[rbase + ccol];
        if (EPI == 0 || EPI == 2)
          Cb[rbase + ccol] = __float2bfloat16(v);
        else
          Cf[rbase + ccol] = v;
      }
    }
  }
}

// ---- split-K reduce: out = out(res) + p0 + p1 + bias[col]; 4096x1024 f32 ----
__global__ __launch_bounds__(256) void ff2_reduce(
    const float* __restrict__ p0, const float* __restrict__ p1,
    const float* __restrict__ bias, float* __restrict__ out) {
  const int idx = blockIdx.x * 256 + threadIdx.x;  // float4 index
  float4 a = ((const float4*)out)[idx];
  const float4 x = ((const float4*)p0)[idx];
  const float4 y = ((const float4*)p1)[idx];
  const float4 bb = ((const float4*)bias)[idx & 255];
  a.x += x.x + y.x + bb.x;
  a.y += x.y + y.y + bb.y;
  a.z += x.z + y.z + bb.z;
  a.w += x.w + y.w + bb.w;
  ((float4*)out)[idx] = a;
}

// ---------------- flash attention (swapped QK^T, async-K, dbuf, T14 V) -------
__global__ __launch_bounds__(256) void attn_kernel(
    const bf16* __restrict__ QKV, const int* __restrict__ pmask,
    bf16* __restrict__ Oout) {
  const int bh = blockIdx.y;
  const int b = bh >> 4, h = bh & 15;
  const int q0 = blockIdx.x << 7;
  const int t = threadIdx.x;
  const int w = t >> 6, l = t & 63;
  const int lq = l & 31, hi = l >> 5;

  __shared__ __align__(16) char smem[32768];

  const long base = (long)b * 2048 * 3072;
  const bf16* Qg = QKV + base + h * 64;
  const bf16* Kg = QKV + base + 1024 + h * 64;
  const bf16* Vg = QKV + base + 2048 + h * 64;

  int kSrc[2];
#pragma unroll
  for (int p = 0; p < 2; ++p) {
    const int r = w * 16 + p * 8 + (l >> 3);
    kSrc[p] = r * 3072 + (((l & 7) ^ (r & 7)) << 3);
  }
  const int vr0 = t >> 3, vsg = t & 7;

  // Q fragments prescaled by log2(e)/8 (base-2 softmax)
  const int qw0 = q0 + w * 32;
  bf16x8 qf[4];
#pragma unroll
  for (int dc = 0; dc < 4; ++dc) {
    uint4 raw = *(const uint4*)(Qg + (long)(qw0 + lq) * 3072 + dc * 16 + hi * 8);
    union { uint4 u4; ushort us[8]; } in; in.u4 = raw;
    union { bf16x8 v; ushort us[8]; } o;
#pragma unroll
    for (int e = 0; e < 8; ++e) o.us[e] = f2bf_bits(0.18033688011f * bfbits2f(in.us[e]));
    qf[dc] = o.v;
  }

  union { unsigned int u[4]; bf16x8 v; } bones;
  bones.u[0] = (hi == 0) ? 0x00003F80u : 0u;
  bones.u[1] = bones.u[2] = bones.u[3] = 0u;

  uint4 vreg[2];
#pragma unroll
  for (int p = 0; p < 2; ++p) {
    vreg[p] = *(const uint4*)(Vg + (long)(p * 32 + vr0) * 3072 + vsg * 8);
    async_copy16(Kg + kSrc[p], smem + w * 2048 + p * 1024);
  }
#pragma unroll
  for (int p = 0; p < 2; ++p) {
    const int r = p * 32 + vr0;
    const ushort* vs = (const ushort*)&vreg[p];
#pragma unroll
    for (int e = 0; e < 8; ++e) {
      const int d = vsg * 8 + e;
      *(ushort*)(smem + 16384 + d * 128 + ((r * 2) ^ (((e ^ vsg) & 7) << 4))) = vs[e];
    }
  }

  f32x16 oacc[2];
#pragma unroll
  for (int nt = 0; nt < 2; ++nt)
#pragma unroll
    for (int r = 0; r < 16; ++r) oacc[nt][r] = 0.f;
  float mrun = -3.0e38f, lsum = 0.f;
  int cur = 0;

  __syncthreads();

  for (int ktg = 0; ktg < 32; ++ktg) {
    if (ktg < 31) {
      const long nrow0 = (long)(ktg + 1) * 64 * 3072;
#pragma unroll
      for (int p = 0; p < 2; ++p) {
        vreg[p] = *(const uint4*)(Vg + nrow0 + (long)(p * 32 + vr0) * 3072 + vsg * 8);
        async_copy16(Kg + nrow0 + kSrc[p], smem + (cur ^ 1) * 8192 + w * 2048 + p * 1024);
      }
    }
    const int k0 = ktg << 6;
    const char* Ks = smem + cur * 8192;
    const char* Vt = smem + 16384 + cur * 8192;

    f32x16 sacc[2];
#pragma unroll
    for (int kt = 0; kt < 2; ++kt) {
#pragma unroll
      for (int r = 0; r < 16; ++r) sacc[kt][r] = 0.f;
#pragma unroll
      for (int dc = 0; dc < 4; ++dc) {
        bf16x8 ka = *(const bf16x8*)(Ks +
            ((kt * 32 + lq) * 128 + ((dc * 32 + hi * 16) ^ ((lq & 7) << 4))));
        sacc[kt] = __builtin_amdgcn_mfma_f32_32x32x16_bf16(ka, qf[dc], sacc[kt], 0, 0, 0);
      }
      const int mv = pmask[b * 2048 + k0 + kt * 32 + lq];
      union { unsigned int u[4]; bf16x8 v; } aadd;
      aadd.u[0] = (hi == 0 && mv == 0) ? (unsigned int)f2bf_bits(-1.0e9f) : 0u;
      aadd.u[1] = aadd.u[2] = aadd.u[3] = 0u;
      sacc[kt] = __builtin_amdgcn_mfma_f32_32x32x16_bf16(aadd.v, bones.v, sacc[kt], 0, 0, 0);
    }

    float tmax = -3.0e38f;
#pragma unroll
    for (int kt = 0; kt < 2; ++kt)
#pragma unroll
      for (int r = 0; r < 16; ++r) tmax = fmaxf(tmax, sacc[kt][r]);
    tmax = fmaxf(tmax, __shfl_xor(tmax, 32));
    const bool need = (bool)__any(tmax > mrun + 8.0f);
    const float mnew = need ? fmaxf(mrun, tmax) : mrun;
    float psum = 0.f;
#pragma unroll
    for (int kt = 0; kt < 2; ++kt)
#pragma unroll
      for (int r = 0; r < 16; ++r) {
        const float p = exp2f(sacc[kt][r] - mnew);
        sacc[kt][r] = p;
        psum += p;
      }
    psum += __shfl_xor(psum, 32);
    if (need) {
      const float alpha = exp2f(mrun - mnew);
      mrun = mnew;
      lsum = lsum * alpha + psum;
#pragma unroll
      for (int r = 0; r < 16; ++r) {
        const float ar = __shfl(alpha, (r & 3) + 8 * (r >> 2) + 4 * hi);
        oacc[0][r] *= ar;
        oacc[1][r] *= ar;
      }
    } else {
      lsum += psum;
    }

    union { unsigned int u[4]; bf16x8 v; } paE[2], paO[2];
#pragma unroll
    for (int kt = 0; kt < 2; ++kt) {
      const unsigned int cs0 = pk2(sacc[kt][0], sacc[kt][1]);
      const unsigned int cs1 = pk2(sacc[kt][2], sacc[kt][3]);
      const unsigned int cs2 = pk2(sacc[kt][4], sacc[kt][5]);
      const unsigned int cs3 = pk2(sacc[kt][6], sacc[kt][7]);
      const unsigned int cs4 = pk2(sacc[kt][8], sacc[kt][9]);
      const unsigned int cs5 = pk2(sacc[kt][10], sacc[kt][11]);
      const unsigned int cs6 = pk2(sacc[kt][12], sacc[kt][13]);
      const unsigned int cs7 = pk2(sacc[kt][14], sacc[kt][15]);
      const unsigned int es0 = __shfl_xor(cs0, 32);
      const unsigned int es1 = __shfl_xor(cs1, 32);
      const unsigned int es2 = __shfl_xor(cs2, 32);
      const unsigned int es3 = __shfl_xor(cs3, 32);
      const unsigned int es4 = __shfl_xor(cs4, 32);
      const unsigned int es5 = __shfl_xor(cs5, 32);
      const unsigned int es6 = __shfl_xor(cs6, 32);
      const unsigned int es7 = __shfl_xor(cs7, 32);
      paE[kt].u[0] = hi ? es2 : cs0;
      paE[kt].u[1] = hi ? es3 : cs1;
      paE[kt].u[2] = hi ? cs2 : es0;
      paE[kt].u[3] = hi ? cs3 : es1;
      paO[kt].u[0] = hi ? es6 : cs4;
      paO[kt].u[1] = hi ? es7 : cs5;
      paO[kt].u[2] = hi ? cs6 : es4;
      paO[kt].u[3] = hi ? cs7 : es5;
    }

#pragma unroll
    for (int kt = 0; kt < 2; ++kt)
#pragma unroll
      for (int nt = 0; nt < 2; ++nt) {
        const int vrow = nt * 32 + lq;
        const int vsw = ((vrow & 7) ^ ((vrow >> 3) & 7)) << 4;
        bf16x8 vbE = *(const bf16x8*)(Vt + (vrow * 128 + ((kt * 64 + hi * 16) ^ vsw)));
        oacc[nt] = __builtin_amdgcn_mfma_f32_32x32x16_bf16(paE[kt].v, vbE, oacc[nt], 0, 0, 0);
        bf16x8 vbO = *(const bf16x8*)(Vt + (vrow * 128 + ((kt * 64 + 32 + hi * 16) ^ vsw)));
        oacc[nt] = __builtin_amdgcn_mfma_f32_32x32x16_bf16(paO[kt].v, vbO, oacc[nt], 0, 0, 0);
      }

    if (ktg < 31) {
      char* VtN = smem + 16384 + (cur ^ 1) * 8192;
#pragma unroll
      for (int p = 0; p < 2; ++p) {
        const int r = p * 32 + vr0;
        const ushort* vs = (const ushort*)&vreg[p];
#pragma unroll
        for (int e = 0; e < 8; ++e) {
          const int d = vsg * 8 + e;
          *(ushort*)(VtN + d * 128 + ((r * 2) ^ (((e ^ vsg) & 7) << 4))) = vs[e];
        }
      }
    }

    __syncthreads();
    cur ^= 1;
  }

  const float inv = 1.0f / lsum;
#pragma unroll
  for (int r = 0; r < 16; ++r) {
    const int crow = (r & 3) + 8 * (r >> 2) + 4 * hi;
    const float ir = __shfl(inv, crow);
    const long orow = (long)b * 2048 + qw0 + crow;
#pragma unroll
    for (int nt = 0; nt < 2; ++nt)
      Oout[orow * 1024 + h * 64 + nt * 32 + lq] = __float2bfloat16(oacc[nt][r] * ir);
  }
}

extern "C" void kernel_launch(void* const* d_in, const int* in_sizes, int n_in,
                              void* d_out, int out_size, void* d_ws, size_t ws_size,
                              hipStream_t stream) {
  const float* X = (const float*)d_in[0];
  const int* pmask = (const int*)d_in[1];
  const float* W_Q = (const float*)d_in[2];
  const float* W_K = (const float*)d_in[3];
  const float* W_V = (const float*)d_in[4];
  const float* W_O = (const float*)d_in[5];
  const float* g1 = (const float*)d_in[6];
  const float* b1 = (const float*)d_in[7];
  const float* W1 = (const float*)d_in[8];
  const float* bias1 = (const float*)d_in[9];
  const float* W2 = (const float*)d_in[10];
  const float* bias2 = (const float*)d_in[11];
  const float* g2 = (const float*)d_in[12];
  const float* b2 = (const float*)d_in[13];
  (void)in_sizes; (void)n_in; (void)out_size; (void)ws_size;

  char* ws = (char*)d_ws;
  const size_t MB = 1ull << 20;
  // layout (80 MB):
  //   [0,8): W1_t           (dead after FF1; p1 overlays [0,16) during FF2)
  //   [8,14): Wqkv_t  [14,16): Wo_t   (contiguous for merged transpose)
  //   [16,24): W2_t
  //   [24,32): xn (LN1 out; later LN2 out)
  //   [32,56): QKV  [56,64): attnb;  ff1 (32MB) overlays [32,64) after attn
  //   [64,80): p0
  // post-attention residual lives in d_out (f32 4096x1024).
  bf16* W1_t   = (bf16*)(ws + 0);
  bf16* Wqkv_t = (bf16*)(ws + 8 * MB);
  bf16* Wo_t   = (bf16*)(ws + 14 * MB);
  bf16* W2_t   = (bf16*)(ws + 16 * MB);
  bf16* xn     = (bf16*)(ws + 24 * MB);
  bf16* QKV    = (bf16*)(ws + 32 * MB);
  bf16* attnb  = (bf16*)(ws + 56 * MB);
  bf16* ff1    = (bf16*)(ws + 32 * MB);
  float* p0    = (float*)(ws + 64 * MB);
  float* p1    = (float*)(ws + 0);
  float* res1  = (float*)d_out;

  transpose_qkvo<<<dim3(32, 32, 4), 256, 0, stream>>>(W_Q, W_K, W_V, W_O, Wqkv_t);
  transpose_to_bf16<<<dim3(128, 32), 256, 0, stream>>>(W1, W1_t, 1024, 4096);
  transpose_to_bf16<<<dim3(32, 128), 256, 0, stream>>>(W2, W2_t, 4096, 1024);

  ln_kernel<<<4096, 256, 0, stream>>>(X, g1, b1, xn);
  gemm_bt<0, 1><<<32 * 24, 256, 0, stream>>>(xn, Wqkv_t, 4096, 3072, 1024, 1024, 1024,
                                             nullptr, nullptr, nullptr, QKV);
  attn_kernel<<<dim3(16, 32), 256, 0, stream>>>(QKV, pmask, attnb);
  gemm_bt<1, 1><<<32 * 8, 256, 0, stream>>>(attnb, Wo_t, 4096, 1024, 1024, 1024, 1024,
                                            nullptr, X, nullptr, res1);
  ln_kernel<<<4096, 256, 0, stream>>>(res1, g2, b2, xn);
  gemm_bt<2, 1><<<32 * 32, 256, 0, stream>>>(xn, W1_t, 4096, 4096, 1024, 1024, 1024,
                                             bias1, nullptr, nullptr, ff1);
  gemm_bt<4, 2><<<2 * 32 * 8, 256, 0, stream>>>(ff1, W2_t, 4096, 1024, 2048, 4096, 4096,
                                                nullptr, nullptr, p1, p0);
  ff2_reduce<<<4096, 256, 0, stream>>>(p0, p1, bias2, res1);
}